// Round 2
// baseline (365.810 us; speedup 1.0000x reference)
//
#include <hip/hip_runtime.h>

typedef __bf16 bf16x8 __attribute__((ext_vector_type(8)));
typedef float f32x4 __attribute__((ext_vector_type(4)));

#define AS1 __attribute__((address_space(1)))
#define AS3 __attribute__((address_space(3)))

// RNE fp32 -> bf16 bits (inputs finite)
static __device__ __forceinline__ unsigned short f2bf(float f) {
  unsigned int u = __float_as_uint(f);
  u += 0x7FFFu + ((u >> 16) & 1u);
  return (unsigned short)(u >> 16);
}

// Fused convert: blocks [0, xBlocks) convert x (fp32->bf16), the rest convert
// w (int32->bf16). 8 elements/thread: 2x dwordx4 load + 1x dwordx4 store.
__global__ __launch_bounds__(256) void cvt_kernel(
    const float4* __restrict__ x, const int4* __restrict__ w,
    ushort4* __restrict__ xo, ushort4* __restrict__ wo,
    int xBlocks, int n4x, int n4w) {
  if (blockIdx.x < xBlocks) {
    int i = (blockIdx.x * blockDim.x + threadIdx.x) * 2;
    if (i + 1 >= n4x) return;
    float4 a = x[i], b = x[i + 1];
    ushort4 oa, ob;
    oa.x = f2bf(a.x); oa.y = f2bf(a.y); oa.z = f2bf(a.z); oa.w = f2bf(a.w);
    ob.x = f2bf(b.x); ob.y = f2bf(b.y); ob.z = f2bf(b.z); ob.w = f2bf(b.w);
    xo[i] = oa; xo[i + 1] = ob;
  } else {
    int i = ((blockIdx.x - xBlocks) * blockDim.x + threadIdx.x) * 2;
    if (i + 1 >= n4w) return;
    int4 a = w[i], b = w[i + 1];
    ushort4 oa, ob;
    oa.x = f2bf((float)a.x); oa.y = f2bf((float)a.y);
    oa.z = f2bf((float)a.z); oa.w = f2bf((float)a.w);
    ob.x = f2bf((float)b.x); ob.y = f2bf((float)b.y);
    ob.z = f2bf((float)b.z); ob.w = f2bf((float)b.w);
    wo[i] = oa; wo[i + 1] = ob;
  }
}

// C[M][N] = A[M][K] * B[N][K]^T * scaler[N]   (bf16 in, fp32 acc/out)
// m97 structure + XCD-aware swizzle: XCD (lid&7) owns a 4-M-tile strip
// (A strip = 4 MB = one XCD L2), N swept in lockstep so B stays hot in L3.
__global__ __launch_bounds__(256) void gemm_bt_kernel(
    const unsigned short* __restrict__ A,   // [M][K] bf16 bits
    const unsigned short* __restrict__ B,   // [N][K] bf16 bits
    const float* __restrict__ scaler,       // [N]
    float* __restrict__ C,                  // [M][N] fp32
    int M, int N, int K)
{
  __shared__ unsigned short sA[128 * 32];
  __shared__ unsigned short sB[128 * 32];

  const int tid  = threadIdx.x;
  const int wave = tid >> 6;
  const int lane = tid & 63;

  // XCD swizzle: lid%8 = XCD (round-robin dispatch heuristic; perf-only).
  // XCD k gets m-tiles [4k, 4k+4) x all n-tiles.
  const int lid = blockIdx.y * gridDim.x + blockIdx.x;
  const int xcd = lid & 7;
  const int s   = lid >> 3;                 // 0..127
  const int mt  = (xcd << 2) | (s & 3);     // 0..31
  const int nt  = s >> 2;                   // 0..31
  const int bm = mt << 7;
  const int bn = nt << 7;

  const int wm = (wave >> 1) << 6;
  const int wn = (wave & 1) << 6;
  const int l15  = lane & 15;
  const int quad = lane >> 4;

  // Staging: wave w covers LDS rows [w*16 + r*64), lane -> row w*16+lane/4,
  // k-offset (lane&3)*8. Unpadded [128][32] layout (global_load_lds order).
  const int srow  = wave * 16 + (lane >> 2);
  const int skoff = (lane & 3) * 8;
  const unsigned short* ga = A + (size_t)(bm + srow) * K + skoff;
  const unsigned short* gb = B + (size_t)(bn + srow) * K + skoff;
  const size_t rstep = (size_t)64 * K;

  unsigned short* lA = &sA[wave * 512];
  unsigned short* lB = &sB[wave * 512];

  f32x4 acc[4][4] = {};

  for (int k0 = 0; k0 < K; k0 += 32) {
    __builtin_amdgcn_global_load_lds((AS1 void*)(ga + k0),         (AS3 void*)lA,           16, 0, 0);
    __builtin_amdgcn_global_load_lds((AS1 void*)(ga + k0 + rstep), (AS3 void*)(lA + 2048),  16, 0, 0);
    __builtin_amdgcn_global_load_lds((AS1 void*)(gb + k0),         (AS3 void*)lB,           16, 0, 0);
    __builtin_amdgcn_global_load_lds((AS1 void*)(gb + k0 + rstep), (AS3 void*)(lB + 2048),  16, 0, 0);
    __syncthreads();

    bf16x8 av[4], bv[4];
    #pragma unroll
    for (int mi = 0; mi < 4; ++mi)
      av[mi] = *(const bf16x8*)&sA[(wm + mi * 16 + l15) * 32 + quad * 8];
    #pragma unroll
    for (int ni = 0; ni < 4; ++ni)
      bv[ni] = *(const bf16x8*)&sB[(wn + ni * 16 + l15) * 32 + quad * 8];

    #pragma unroll
    for (int mi = 0; mi < 4; ++mi)
      #pragma unroll
      for (int ni = 0; ni < 4; ++ni)
        acc[mi][ni] = __builtin_amdgcn_mfma_f32_16x16x32_bf16(av[mi], bv[ni], acc[mi][ni], 0, 0, 0);
    __syncthreads();
  }

  // Epilogue: C/D layout col=lane&15 (N), row=quad*4+reg (M); scaler in fp32.
  #pragma unroll
  for (int ni = 0; ni < 4; ++ni) {
    int gn = bn + wn + ni * 16 + l15;
    float sc = scaler[gn];
    #pragma unroll
    for (int mi = 0; mi < 4; ++mi) {
      int gm0 = bm + wm + mi * 16 + quad * 4;
      #pragma unroll
      for (int r = 0; r < 4; ++r)
        C[(size_t)(gm0 + r) * N + gn] = acc[mi][ni][r] * sc;
    }
  }
}

extern "C" void kernel_launch(void* const* d_in, const int* in_sizes, int n_in,
                              void* d_out, int out_size, void* d_ws, size_t ws_size,
                              hipStream_t stream) {
  const float* x  = (const float*)d_in[0];          // [B,S,K] fp32
  const int*   w  = (const int*)d_in[1];            // [N,K] int32 (int8 range)
  const float* sc = (const float*)d_in[2];          // [N] fp32
  float* out = (float*)d_out;

  const int N = in_sizes[2];                        // 4096
  const int K = in_sizes[1] / N;                    // 4096
  const int M = in_sizes[0] / K;                    // 4096

  unsigned short* Abf = (unsigned short*)d_ws;              // [M][K] bf16
  unsigned short* Wbf = Abf + (size_t)M * K;                // [N][K] bf16

  int n4x = (M * K) / 4, n4w = (N * K) / 4;
  int xBlocks = (n4x / 2 + 255) / 256;              // 8 elems/thread
  int wBlocks = (n4w / 2 + 255) / 256;
  cvt_kernel<<<xBlocks + wBlocks, 256, 0, stream>>>(
      (const float4*)x, (const int4*)w, (ushort4*)Abf, (ushort4*)Wbf,
      xBlocks, n4x, n4w);

  dim3 grid(N / 128, M / 128);
  gemm_bt_kernel<<<grid, 256, 0, stream>>>(Abf, Wbf, sc, out, M, N, K);
}

// Round 3
// 327.295 us; speedup vs baseline: 1.1177x; 1.1177x over previous
//
#include <hip/hip_runtime.h>

typedef __bf16 bf16x8 __attribute__((ext_vector_type(8)));
typedef float f32x4 __attribute__((ext_vector_type(4)));

#define AS1 __attribute__((address_space(1)))
#define AS3 __attribute__((address_space(3)))

// RNE fp32 -> bf16 bits (inputs finite)
static __device__ __forceinline__ unsigned short f2bf(float f) {
  unsigned int u = __float_as_uint(f);
  u += 0x7FFFu + ((u >> 16) & 1u);
  return (unsigned short)(u >> 16);
}

// Fused convert: blocks [0, xBlocks) convert x (fp32->bf16), rest convert
// w (int32->bf16). 8 elements/thread.
__global__ __launch_bounds__(256) void cvt_kernel(
    const float4* __restrict__ x, const int4* __restrict__ w,
    ushort4* __restrict__ xo, ushort4* __restrict__ wo,
    int xBlocks, int n4x, int n4w) {
  if (blockIdx.x < xBlocks) {
    int i = (blockIdx.x * blockDim.x + threadIdx.x) * 2;
    if (i + 1 >= n4x) return;
    float4 a = x[i], b = x[i + 1];
    ushort4 oa, ob;
    oa.x = f2bf(a.x); oa.y = f2bf(a.y); oa.z = f2bf(a.z); oa.w = f2bf(a.w);
    ob.x = f2bf(b.x); ob.y = f2bf(b.y); ob.z = f2bf(b.z); ob.w = f2bf(b.w);
    xo[i] = oa; xo[i + 1] = ob;
  } else {
    int i = ((blockIdx.x - xBlocks) * blockDim.x + threadIdx.x) * 2;
    if (i + 1 >= n4w) return;
    int4 a = w[i], b = w[i + 1];
    ushort4 oa, ob;
    oa.x = f2bf((float)a.x); oa.y = f2bf((float)a.y);
    oa.z = f2bf((float)a.z); oa.w = f2bf((float)a.w);
    ob.x = f2bf((float)b.x); ob.y = f2bf((float)b.y);
    ob.z = f2bf((float)b.z); ob.w = f2bf((float)b.w);
    wo[i] = oa; wo[i + 1] = ob;
  }
}

// C[M][N] = A[M][K] * B[N][K]^T * scaler[N]   (bf16 in, fp32 acc/out)
// m97 structure with BK=64: two BK=32 sub-tiles (LDS [2][128][32], each the
// proven unpadded layout) staged behind ONE barrier pair -> 64 barriers
// instead of 128, 32 MFMA per drain instead of 16.
__global__ __launch_bounds__(256) void gemm_bt_kernel(
    const unsigned short* __restrict__ A,   // [M][K] bf16 bits
    const unsigned short* __restrict__ B,   // [N][K] bf16 bits
    const float* __restrict__ scaler,       // [N]
    float* __restrict__ C,                  // [M][N] fp32
    int M, int N, int K)
{
  __shared__ unsigned short sA[2 * 128 * 32];
  __shared__ unsigned short sB[2 * 128 * 32];

  const int tid  = threadIdx.x;
  const int wave = tid >> 6;
  const int lane = tid & 63;
  const int bm = blockIdx.y << 7;
  const int bn = blockIdx.x << 7;

  const int wm = (wave >> 1) << 6;   // 2x2 wave grid over the 128x128 tile
  const int wn = (wave & 1) << 6;
  const int l15  = lane & 15;
  const int quad = lane >> 4;

  // Staging map (per BK=32 sub-tile, identical to proven layout): wave w,
  // round r covers LDS rows [r*64 + w*16, +16); lane -> row w*16+lane/4,
  // k-offset (lane&3)*8. Unpadded [128][32] (global_load_lds lane order).
  const int srow  = wave * 16 + (lane >> 2);
  const int skoff = (lane & 3) * 8;
  const unsigned short* ga = A + (size_t)(bm + srow) * K + skoff;
  const unsigned short* gb = B + (size_t)(bn + srow) * K + skoff;
  const size_t rstep = (size_t)64 * K;      // +64 rows for round 1

  // Wave-uniform LDS bases: sub-tile ks at +ks*4096 elems, round r at +r*2048.
  unsigned short* lA = &sA[wave * 512];
  unsigned short* lB = &sB[wave * 512];

  f32x4 acc[4][4] = {};

  for (int k0 = 0; k0 < K; k0 += 64) {
    #pragma unroll
    for (int ks = 0; ks < 2; ++ks) {
      const int kk = k0 + ks * 32;
      const int lo = ks * 4096;
      __builtin_amdgcn_global_load_lds((AS1 void*)(ga + kk),         (AS3 void*)(lA + lo),        16, 0, 0);
      __builtin_amdgcn_global_load_lds((AS1 void*)(ga + kk + rstep), (AS3 void*)(lA + lo + 2048), 16, 0, 0);
      __builtin_amdgcn_global_load_lds((AS1 void*)(gb + kk),         (AS3 void*)(lB + lo),        16, 0, 0);
      __builtin_amdgcn_global_load_lds((AS1 void*)(gb + kk + rstep), (AS3 void*)(lB + lo + 2048), 16, 0, 0);
    }
    __syncthreads();   // one vmcnt(0) drain per 64 K-steps (was per 32)

    #pragma unroll
    for (int ks = 0; ks < 2; ++ks) {
      const int lo = ks * 4096;
      bf16x8 av[4], bv[4];
      #pragma unroll
      for (int mi = 0; mi < 4; ++mi)
        av[mi] = *(const bf16x8*)&sA[lo + (wm + mi * 16 + l15) * 32 + quad * 8];
      #pragma unroll
      for (int ni = 0; ni < 4; ++ni)
        bv[ni] = *(const bf16x8*)&sB[lo + (wn + ni * 16 + l15) * 32 + quad * 8];

      #pragma unroll
      for (int mi = 0; mi < 4; ++mi)
        #pragma unroll
        for (int ni = 0; ni < 4; ++ni)
          acc[mi][ni] = __builtin_amdgcn_mfma_f32_16x16x32_bf16(av[mi], bv[ni], acc[mi][ni], 0, 0, 0);
    }
    __syncthreads();
  }

  // Epilogue: C/D layout col=lane&15 (N), row=quad*4+reg (M); scaler in fp32.
  #pragma unroll
  for (int ni = 0; ni < 4; ++ni) {
    int gn = bn + wn + ni * 16 + l15;
    float sc = scaler[gn];
    #pragma unroll
    for (int mi = 0; mi < 4; ++mi) {
      int gm0 = bm + wm + mi * 16 + quad * 4;
      #pragma unroll
      for (int r = 0; r < 4; ++r)
        C[(size_t)(gm0 + r) * N + gn] = acc[mi][ni][r] * sc;
    }
  }
}

extern "C" void kernel_launch(void* const* d_in, const int* in_sizes, int n_in,
                              void* d_out, int out_size, void* d_ws, size_t ws_size,
                              hipStream_t stream) {
  const float* x  = (const float*)d_in[0];          // [B,S,K] fp32
  const int*   w  = (const int*)d_in[1];            // [N,K] int32 (int8 range)
  const float* sc = (const float*)d_in[2];          // [N] fp32
  float* out = (float*)d_out;

  const int N = in_sizes[2];                        // 4096
  const int K = in_sizes[1] / N;                    // 4096
  const int M = in_sizes[0] / K;                    // 4096

  unsigned short* Abf = (unsigned short*)d_ws;              // [M][K] bf16
  unsigned short* Wbf = Abf + (size_t)M * K;                // [N][K] bf16

  int n4x = (M * K) / 4, n4w = (N * K) / 4;
  int xBlocks = (n4x / 2 + 255) / 256;              // 8 elems/thread
  int wBlocks = (n4w / 2 + 255) / 256;
  cvt_kernel<<<xBlocks + wBlocks, 256, 0, stream>>>(
      (const float4*)x, (const int4*)w, (ushort4*)Abf, (ushort4*)Wbf,
      xBlocks, n4x, n4w);

  dim3 grid(N / 128, M / 128);
  gemm_bt_kernel<<<grid, 256, 0, stream>>>(Abf, Wbf, sc, out, M, N, K);
}

// Round 4
// 244.906 us; speedup vs baseline: 1.4937x; 1.3364x over previous
//
#include <hip/hip_runtime.h>

typedef int i32x4 __attribute__((ext_vector_type(4)));

#define AS1 __attribute__((address_space(1)))
#define AS3 __attribute__((address_space(3)))

// ---------------------------------------------------------------------------
// Quantize kernel. Blocks [0, M): per-token dynamic quant of x row r
// (4096 fp32 -> int8, scale sx[r] = rowmax/127). Blocks [M, M+wB): narrow
// w int32 (values 0..126, exact) -> int8. 16 elems/thread everywhere.
// ---------------------------------------------------------------------------
__global__ __launch_bounds__(256) void quant_kernel(
    const float4* __restrict__ x, const int4* __restrict__ w,
    signed char* __restrict__ xq, signed char* __restrict__ wq,
    float* __restrict__ sx, int M, int Kq) {   // Kq = K/16 int4-groups per row
  const int tid = threadIdx.x;
  if ((int)blockIdx.x < M) {
    const int r = blockIdx.x;
    // row r: thread reads 16 consecutive floats at elem r*4096 + tid*16
    float4 v[4];
    #pragma unroll
    for (int j = 0; j < 4; ++j) v[j] = x[(size_t)r * 1024 + tid * 4 + j];
    float m = 0.f;
    #pragma unroll
    for (int j = 0; j < 4; ++j)
      m = fmaxf(m, fmaxf(fmaxf(fabsf(v[j].x), fabsf(v[j].y)),
                         fmaxf(fabsf(v[j].z), fabsf(v[j].w))));
    #pragma unroll
    for (int off = 1; off < 64; off <<= 1) m = fmaxf(m, __shfl_xor(m, off));
    __shared__ float wmax[4];
    if ((tid & 63) == 0) wmax[tid >> 6] = m;
    __syncthreads();
    m = fmaxf(fmaxf(wmax[0], wmax[1]), fmaxf(wmax[2], wmax[3]));
    const float inv = (m > 0.f) ? 127.0f / m : 0.f;
    if (tid == 0) sx[r] = m * (1.0f / 127.0f);
    signed char q[16];
    #pragma unroll
    for (int j = 0; j < 4; ++j) {
      q[j * 4 + 0] = (signed char)__float2int_rn(v[j].x * inv);
      q[j * 4 + 1] = (signed char)__float2int_rn(v[j].y * inv);
      q[j * 4 + 2] = (signed char)__float2int_rn(v[j].z * inv);
      q[j * 4 + 3] = (signed char)__float2int_rn(v[j].w * inv);
    }
    ((int4*)xq)[(size_t)r * 256 + tid] = *(const int4*)q;
  } else {
    const int b = blockIdx.x - M;
    int4 v[4];
    #pragma unroll
    for (int j = 0; j < 4; ++j) v[j] = w[(size_t)b * 1024 + tid * 4 + j];
    signed char q[16];
    #pragma unroll
    for (int j = 0; j < 4; ++j) {
      q[j * 4 + 0] = (signed char)v[j].x; q[j * 4 + 1] = (signed char)v[j].y;
      q[j * 4 + 2] = (signed char)v[j].z; q[j * 4 + 3] = (signed char)v[j].w;
    }
    ((int4*)wq)[(size_t)b * 256 + tid] = *(const int4*)q;
  }
}

// ---------------------------------------------------------------------------
// C[M][N] = (Aq[M][K] . Bq[N][K]^T) * sx[M] * scaler[N]
// i8 MFMA 16x16x64, 128x128 tile, BK=128 (32 KB LDS), 64 barriers total.
// LDS layout: row-major [128][128] i8 with XOR-swizzled 16B k-groups:
//   phys_kgroup = logical_kgroup ^ (row & 7)
// applied in BOTH the staging global read (LDS dest stays base+lane*16, as
// global_load_lds requires) and the fragment ds_read -> 2-way banks (free).
// ---------------------------------------------------------------------------
__global__ __launch_bounds__(256) void gemm_i8_kernel(
    const signed char* __restrict__ A,   // [M][K] i8
    const signed char* __restrict__ B,   // [N][K] i8
    const float* __restrict__ sx,        // [M] x dequant scale
    const float* __restrict__ scaler,    // [N] weight scale
    float* __restrict__ C,               // [M][N] fp32
    int M, int N, int K)
{
  __shared__ signed char sA[128 * 128];
  __shared__ signed char sB[128 * 128];

  const int tid  = threadIdx.x;
  const int wave = tid >> 6;
  const int lane = tid & 63;
  const int bm = blockIdx.y << 7;
  const int bn = blockIdx.x << 7;

  const int wm = (wave >> 1) << 6;   // 2x2 wave grid, 64x64 out per wave
  const int wn = (wave & 1) << 6;
  const int l15  = lane & 15;
  const int quad = lane >> 4;

  // Staging: call c covers tile-rows [c*32,(c+1)*32); wave w rows w*8+lane/8.
  // slot = lane&7 holds phys k-group slot; its logical kgroup = slot ^ (row&7)
  // with row&7 == lane>>3 (c*32, w*8 are multiples of 8).
  const int l8 = lane >> 3;                       // row&7
  const int kg = (lane & 7) ^ l8;                 // logical kgroup to fetch
  const signed char* ga = A + (size_t)(bm + wave * 8 + l8) * K + kg * 16;
  const signed char* gb = B + (size_t)(bn + wave * 8 + l8) * K + kg * 16;
  const size_t cstep = (size_t)32 * K;            // +32 rows per call

  signed char* lA = &sA[wave * 1024];             // wave-uniform LDS base
  signed char* lB = &sB[wave * 1024];

  i32x4 acc[4][4] = {};

  for (int k0 = 0; k0 < K; k0 += 128) {
    #pragma unroll
    for (int c = 0; c < 4; ++c) {
      __builtin_amdgcn_global_load_lds((AS1 void*)(ga + k0 + c * cstep), (AS3 void*)(lA + c * 4096), 16, 0, 0);
      __builtin_amdgcn_global_load_lds((AS1 void*)(gb + k0 + c * cstep), (AS3 void*)(lB + c * 4096), 16, 0, 0);
    }
    __syncthreads();

    #pragma unroll
    for (int s = 0; s < 2; ++s) {   // two K=64 halves of BK=128
      // A-frag: lane holds A[m=l15][k = s*64 + quad*16 .. +15]
      // phys kgroup = (s*4+quad) ^ (l15&7); 16B-aligned ds_read_b128
      i32x4 av[4], bv[4];
      const int pk = ((s << 2) | quad) ^ (l15 & 7);
      #pragma unroll
      for (int mi = 0; mi < 4; ++mi)
        av[mi] = *(const i32x4*)&sA[(wm + mi * 16 + l15) * 128 + pk * 16];
      #pragma unroll
      for (int ni = 0; ni < 4; ++ni)
        bv[ni] = *(const i32x4*)&sB[(wn + ni * 16 + l15) * 128 + pk * 16];

      #pragma unroll
      for (int mi = 0; mi < 4; ++mi)
        #pragma unroll
        for (int ni = 0; ni < 4; ++ni)
          acc[mi][ni] = __builtin_amdgcn_mfma_i32_16x16x64_i8(av[mi], bv[ni], acc[mi][ni], 0, 0, 0);
    }
    __syncthreads();
  }

  // Epilogue: C/D layout col=lane&15 (N), row=quad*4+reg (M) — dtype-indep.
  // out = i32acc * sx[row] * scaler[col], all fp32 (exact scales).
  #pragma unroll
  for (int mi = 0; mi < 4; ++mi) {
    const int gm0 = bm + wm + mi * 16 + quad * 4;
    float sr[4];
    #pragma unroll
    for (int r = 0; r < 4; ++r) sr[r] = sx[gm0 + r];
    #pragma unroll
    for (int ni = 0; ni < 4; ++ni) {
      const int gn = bn + wn + ni * 16 + l15;
      const float sc = scaler[gn];
      #pragma unroll
      for (int r = 0; r < 4; ++r)
        C[(size_t)(gm0 + r) * N + gn] = (float)acc[mi][ni][r] * sr[r] * sc;
    }
  }
}

extern "C" void kernel_launch(void* const* d_in, const int* in_sizes, int n_in,
                              void* d_out, int out_size, void* d_ws, size_t ws_size,
                              hipStream_t stream) {
  const float* x  = (const float*)d_in[0];          // [B,S,K] fp32
  const int*   w  = (const int*)d_in[1];            // [N,K] int32 (int8 range)
  const float* sc = (const float*)d_in[2];          // [N] fp32
  float* out = (float*)d_out;

  const int N = in_sizes[2];                        // 4096
  const int K = in_sizes[1] / N;                    // 4096
  const int M = in_sizes[0] / K;                    // 4096

  signed char* Aq = (signed char*)d_ws;             // [M][K] i8
  signed char* Bq = Aq + (size_t)M * K;             // [N][K] i8
  float* sx = (float*)(Bq + (size_t)N * K);         // [M] fp32

  const int wBlocks = (N * K) / (256 * 16);         // 16 elems/thread
  quant_kernel<<<M + wBlocks, 256, 0, stream>>>(
      (const float4*)x, (const int4*)w, Aq, Bq, sx, M, K / 16);

  dim3 grid(N / 128, M / 128);
  gemm_i8_kernel<<<grid, 256, 0, stream>>>(Aq, Bq, sx, sc, out, M, N, K);
}